// Round 1
// baseline (136.292 us; speedup 1.0000x reference)
//
#include <hip/hip_runtime.h>

using v4f = float __attribute__((ext_vector_type(4)));

constexpr int NTOK = 32768;       // 16 * 2048 tokens
constexpr int DIMS = 64;
constexpr int KCODES = 1000;
constexpr int TPB = 128;          // tokens per argmin block
constexpr int CHUNK = 128;        // codes staged per LDS chunk
constexpr int CPS = 4;            // chunks per K-split
constexpr float BIG = 3.4e38f;

// ---------------------------------------------------------------- prep
__global__ void vq_prep(const float* __restrict__ emb, float* __restrict__ norms,
                        float* __restrict__ loss_accum, int* __restrict__ usage)
{
    int gid = blockIdx.x * 256 + threadIdx.x;
    if (gid == 0) *loss_accum = 0.f;
    if (gid < KCODES) {
        usage[gid] = 0;
        const float* e = emb + gid * DIMS;
        float s = 0.f;
        #pragma unroll
        for (int d4 = 0; d4 < 16; ++d4) {
            v4f q = *reinterpret_cast<const v4f*>(e + d4 * 4);
            s = fmaf(q[0], q[0], s);
            s = fmaf(q[1], q[1], s);
            s = fmaf(q[2], q[2], s);
            s = fmaf(q[3], q[3], s);
        }
        norms[gid] = s;
    }
}

// ---------------------------------------------------------------- argmin (GEMM-tiled)
__global__ __launch_bounds__(256, 2) void vq_argmin(
    const float* __restrict__ x, const float* __restrict__ emb,
    const float* __restrict__ norms,
    float* __restrict__ pval, int* __restrict__ pidx)
{
    __shared__ float xs[DIMS][TPB];      // [d][token] 32 KB, staged directly from [B,D,L]
    __shared__ float es[CHUNK][68];      // [code][d], pad 64->68: read addr = 68*(tx+16j)+d -> 2-way, free
    __shared__ float ns[CHUNK];

    const int tid   = threadIdx.x;
    const int tblk  = blockIdx.x >> 1;
    const int split = blockIdx.x & 1;
    const int tok0  = tblk * TPB;
    const int b     = tok0 >> 11;        // / 2048 (TPB divides 2048 -> same b for whole tile)
    const int l0    = tok0 & 2047;
    const float* xbase = x + ((size_t)b << 17) + l0;   // x[b][d][l0+t] = xbase[d*2048+t]

    // stage x tile: 64 x 128 floats = 2048 float4, coalesced
    #pragma unroll
    for (int it = 0; it < 8; ++it) {
        int f  = it * 256 + tid;
        int d  = f >> 5;
        int t4 = (f & 31) << 2;
        *reinterpret_cast<v4f*>(&xs[d][t4]) =
            *reinterpret_cast<const v4f*>(xbase + d * 2048 + t4);
    }

    const int ty = tid >> 4;   // 0..15 -> owns tokens ty*8 .. ty*8+7
    const int tx = tid & 15;   // owns codes tx + 16*j within chunk

    float minv[8];
    int   mini[8];
    #pragma unroll
    for (int i = 0; i < 8; ++i) { minv[i] = BIG; mini[i] = 0; }

    for (int cc = 0; cc < CPS; ++cc) {
        const int cbase = (split * CPS + cc) * CHUNK;
        __syncthreads();
        // stage e chunk (coalesced global float4 reads)
        #pragma unroll
        for (int it = 0; it < 8; ++it) {
            int f  = it * 256 + tid;
            int c  = f >> 4;
            int d4 = (f & 15) << 2;
            int gc = cbase + c;
            v4f v = {0.f, 0.f, 0.f, 0.f};
            if (gc < KCODES) v = *reinterpret_cast<const v4f*>(emb + gc * DIMS + d4);
            *reinterpret_cast<v4f*>(&es[c][d4]) = v;
        }
        if (tid < CHUNK) {
            int gc = cbase + tid;
            ns[tid] = (gc < KCODES) ? norms[gc] : 3.0e38f;  // padded codes never win
        }
        __syncthreads();

        float acc[8][8];
        #pragma unroll
        for (int i = 0; i < 8; ++i)
            #pragma unroll
            for (int j = 0; j < 8; ++j) acc[i][j] = 0.f;

        #pragma unroll 4
        for (int d4 = 0; d4 < 16; ++d4) {
            const int d0 = d4 * 4;
            v4f xa[4], xb[4];
            #pragma unroll
            for (int dd = 0; dd < 4; ++dd) {
                xa[dd] = *reinterpret_cast<const v4f*>(&xs[d0 + dd][ty * 8]);
                xb[dd] = *reinterpret_cast<const v4f*>(&xs[d0 + dd][ty * 8 + 4]);
            }
            #pragma unroll
            for (int j = 0; j < 8; ++j) {
                v4f ev = *reinterpret_cast<const v4f*>(&es[tx + 16 * j][d0]);
                #pragma unroll
                for (int dd = 0; dd < 4; ++dd) {
                    const float e = ev[dd];
                    acc[0][j] = fmaf(xa[dd][0], e, acc[0][j]);
                    acc[1][j] = fmaf(xa[dd][1], e, acc[1][j]);
                    acc[2][j] = fmaf(xa[dd][2], e, acc[2][j]);
                    acc[3][j] = fmaf(xa[dd][3], e, acc[3][j]);
                    acc[4][j] = fmaf(xb[dd][0], e, acc[4][j]);
                    acc[5][j] = fmaf(xb[dd][1], e, acc[5][j]);
                    acc[6][j] = fmaf(xb[dd][2], e, acc[6][j]);
                    acc[7][j] = fmaf(xb[dd][3], e, acc[7][j]);
                }
            }
        }

        // fold chunk into running argmin (ascending code index -> strict < keeps first min)
        #pragma unroll
        for (int j = 0; j < 8; ++j) {
            const int c = tx + 16 * j;
            const float nv = ns[c];
            const int gi = cbase + c;
            #pragma unroll
            for (int i = 0; i < 8; ++i) {
                float dist = fmaf(-2.f, acc[i][j], nv);
                if (dist < minv[i]) { minv[i] = dist; mini[i] = gi; }
            }
        }
    }

    // cross-tx (16-lane group) argmin merge, lexicographic (val, idx)
    #pragma unroll
    for (int i = 0; i < 8; ++i) {
        float v = minv[i];
        int  ix = mini[i];
        #pragma unroll
        for (int off = 8; off >= 1; off >>= 1) {
            float vo = __shfl_xor(v, off);
            int   io = __shfl_xor(ix, off);
            if (vo < v || (vo == v && io < ix)) { v = vo; ix = io; }
        }
        if (tx == 0) {
            int token = tok0 + ty * 8 + i;
            pval[split * NTOK + token] = v;
            pidx[split * NTOK + token] = ix;
        }
    }
}

// ---------------------------------------------------------------- merge + gather + loss + usage
__global__ __launch_bounds__(256) void vq_output(
    const float* __restrict__ x, const float* __restrict__ emb,
    const float* __restrict__ pval, const int* __restrict__ pidx,
    float* __restrict__ out, float* __restrict__ idx_f,
    float* __restrict__ loss_accum, int* __restrict__ usage)
{
    const int tid   = threadIdx.x;
    const int token = blockIdx.x * 256 + tid;
    const float v0 = pval[token];
    const float v1 = pval[NTOK + token];
    const int   i0 = pidx[token];
    const int   i1 = pidx[NTOK + token];
    const int   ix = (v1 < v0) ? i1 : i0;   // i0 < i1 always -> ties pick lower idx

    idx_f[token] = (float)ix;
    usage[ix] = 1;

    const int b = token >> 11, l = token & 2047;
    const float* xb = x   + ((size_t)b << 17) + l;
    float*       ob = out + ((size_t)b << 17) + l;
    const float* e  = emb + ix * DIMS;

    float lsum = 0.f;
    #pragma unroll
    for (int d4 = 0; d4 < 16; ++d4) {
        v4f q = *reinterpret_cast<const v4f*>(e + d4 * 4);
        #pragma unroll
        for (int dd = 0; dd < 4; ++dd) {
            const int d = d4 * 4 + dd;
            float xv = xb[(size_t)d * 2048];
            float diff = q[dd] - xv;          // (quantized - inputs)
            lsum += diff * diff;
            ob[(size_t)d * 2048] = xv + diff; // inputs + (quantized - inputs): exact STE forward
        }
    }

    #pragma unroll
    for (int off = 32; off >= 1; off >>= 1) lsum += __shfl_xor(lsum, off);
    __shared__ float bsum[4];
    if ((tid & 63) == 0) bsum[tid >> 6] = lsum;
    __syncthreads();
    if (tid == 0) atomicAdd(loss_accum, bsum[0] + bsum[1] + bsum[2] + bsum[3]);
}

// ---------------------------------------------------------------- finalize scalars
__global__ void vq_finalize(const float* __restrict__ loss_accum, const int* __restrict__ usage,
                            float* __restrict__ o_loss, float* __restrict__ o_usage)
{
    __shared__ int wsum[16];
    int tid = threadIdx.x;   // 1024 threads
    int c = (tid < KCODES && usage[tid]) ? 1 : 0;
    #pragma unroll
    for (int off = 32; off >= 1; off >>= 1) c += __shfl_xor(c, off);
    if ((tid & 63) == 0) wsum[tid >> 6] = c;
    __syncthreads();
    if (tid == 0) {
        int total = 0;
        #pragma unroll
        for (int i = 0; i < 16; ++i) total += wsum[i];
        float s = *loss_accum;
        float m = s / 2097152.0f;           // mean over B*L*D
        o_loss[0]  = m + 10.0f * m;         // q_latent + COMMITMENT_COST * e_latent
        o_usage[0] = (float)total;
    }
}

// ---------------------------------------------------------------- launch
extern "C" void kernel_launch(void* const* d_in, const int* in_sizes, int n_in,
                              void* d_out, int out_size, void* d_ws, size_t ws_size,
                              hipStream_t stream)
{
    const float* x   = (const float*)d_in[0];   // [16, 64, 2048]
    const float* emb = (const float*)d_in[1];   // [1000, 64]

    float* o       = (float*)d_out;
    float* out     = o;                 // 2097152 floats, [B, D, L]
    float* o_loss  = o + 2097152;
    float* o_usage = o + 2097153;
    float* o_idx   = o + 2097154;       // 32768 floats

    char*  ws         = (char*)d_ws;
    float* loss_accum = (float*)(ws);
    int*   usage      = (int*)(ws + 64);
    float* norms      = (float*)(ws + 4096);
    float* pval       = (float*)(ws + 8192);
    int*   pidx       = (int*)(ws + 8192 + 2 * NTOK * sizeof(float));
    // total ws use: ~520 KB

    vq_prep<<<4, 256, 0, stream>>>(emb, norms, loss_accum, usage);
    vq_argmin<<<512, 256, 0, stream>>>(x, emb, norms, pval, pidx);
    vq_output<<<NTOK / 256, 256, 0, stream>>>(x, emb, pval, pidx, out, o_idx, loss_accum, usage);
    vq_finalize<<<1, 1024, 0, stream>>>(loss_accum, usage, o_loss, o_usage);
}